// Round 7
// baseline (204.520 us; speedup 1.0000x reference)
//
#include <hip/hip_runtime.h>
#include <math.h>

#define H 512
#define W 512
#define BAND 8            // rows computed per block
#define STAGE (BAND + 2)  // rows staged per image (with halo)
#define NQ 11             // 0:s0 1-4:s1i..s4i 5-8:s1o..s4o 9:tex 10:shape

typedef __attribute__((address_space(3))) void       lds_void;
typedef const __attribute__((address_space(1))) void g_void;

// async global->LDS DMA, 16 B/lane: lane i's 16 B lands at l + i*16.
__device__ __forceinline__ void async_copy16(const float* g, float* l) {
    __builtin_amdgcn_global_load_lds((g_void*)g, (lds_void*)l, 16, 0, 0);
}

// read 8 px + 1-col halo each side from an LDS row; x0 is lane*8 (32B aligned)
__device__ __forceinline__ void load10(const float* row, int x0, float* a) {
    float4 u = *(const float4*)&row[x0];
    float4 v = *(const float4*)&row[x0 + 4];
    a[0] = (x0 == 0) ? 0.0f : row[x0 - 1];
    a[1] = u.x; a[2] = u.y; a[3] = u.z; a[4] = u.w;
    a[5] = v.x; a[6] = v.y; a[7] = v.z; a[8] = v.w;
    a[9] = (x0 + 8 == W) ? 0.0f : row[x0 + 8];
}

// r6 cooperative-LDS structure (40 KB = 4 blocks/CU) + fused last-block finalize
// (saves the second kernel's dispatch + dependency gap).
__global__ __launch_bounds__(256) void radiomics_fused(
    const float* __restrict__ inp, const float* __restrict__ outp,
    const float* __restrict__ mask, double* __restrict__ partials,
    unsigned int* __restrict__ counter, int nblk, double inv_n,
    float* __restrict__ out4)
{
    __shared__ float lds[2][STAGE][W];          // 40960 B exactly
    __shared__ int amLast;

    const int tid  = threadIdx.x;
    const int lane = tid & 63;
    const int wib  = tid >> 6;                  // wave in block (0..3)
    const int blk  = blockIdx.x;
    const int b    = blk >> 6;                  // image (64 bands/image)
    const int band = blk & 63;
    const int y0   = band * BAND;
    const size_t off = (size_t)b * H * W;
    const int x0   = lane * 8;

    // ---- stage 10 rows x 2 images: 40 segments of 1 KB, 10 per wave ----
    for (int s = wib; s < 2 * STAGE * 2; s += 4) {
        const int img = s / (2 * STAGE);
        const int rem = s - img * (2 * STAGE);
        const int rs  = rem >> 1;               // stage row 0..9
        const int g   = rem & 1;                // 1 KB segment in row
        const int y   = y0 - 1 + rs;
        float* dst = &lds[img][rs][g * 256];
        if (y < 0 || y >= H) {
            *(float4*)&dst[lane * 4] = make_float4(0.f, 0.f, 0.f, 0.f);
        } else {
            const float* src = (img ? outp : inp) + off + (size_t)y * W + g * 256 + lane * 4;
            async_copy16(src, dst);
        }
    }

    // ---- mask rows for this wave's 2 compute rows (register loads, overlap DMA) ----
    const int r0 = y0 + 2 * wib;
    float Mk[16];
    {
        const float4* p = (const float4*)(mask + off + (size_t)r0 * W + x0);
        float4 a = p[0], c = p[1];
        const float4* q = (const float4*)(mask + off + (size_t)(r0 + 1) * W + x0);
        float4 d = q[0], e = q[1];
        Mk[0]=a.x; Mk[1]=a.y; Mk[2]=a.z; Mk[3]=a.w; Mk[4]=c.x; Mk[5]=c.y; Mk[6]=c.z; Mk[7]=c.w;
        Mk[8]=d.x; Mk[9]=d.y; Mk[10]=d.z; Mk[11]=d.w; Mk[12]=e.x; Mk[13]=e.y; Mk[14]=e.z; Mk[15]=e.w;
    }

    __syncthreads();   // drains vmcnt (DMA + mask) and lgkmcnt (zero-fill)

    const float inv9 = 1.0f / 9.0f;
    float acc[NQ];
    #pragma unroll
    for (int q = 0; q < NQ; q++) acc[q] = 0.0f;

    #pragma unroll
    for (int cr = 0; cr < 2; cr++) {
        const int rs = 2 * wib + cr + 1;        // stage index of computed row
        const float* mrow = &Mk[cr * 8];
        float tvI[8], lpI[8];

        // ---- image 0: texture/laplacian + input moments ----
        {
            float A[10], B[10], C[10];
            load10(lds[0][rs - 1], x0, A);
            load10(lds[0][rs],     x0, B);
            load10(lds[0][rs + 1], x0, C);
            float c1[10], c2[10];
            #pragma unroll
            for (int j = 0; j < 10; j++) {
                c1[j] = A[j] + B[j] + C[j];
                c2[j] = fmaf(A[j], A[j], fmaf(B[j], B[j], C[j] * C[j]));
            }
            #pragma unroll
            for (int j = 0; j < 8; j++) {
                float s1 = c1[j] + c1[j+1] + c1[j+2];
                float s2 = c2[j] + c2[j+1] + c2[j+2];
                float mn = s1 * inv9;
                tvI[j] = fmaf(-mn, mn, s2 * inv9);
                lpI[j] = A[j+1] + C[j+1] + B[j] + B[j+2] - 4.0f * B[j+1];
                float m = mrow[j];
                acc[0] += m;
                float x = B[j+1];
                float t = x * m; acc[1] += t; t *= x; acc[2] += t; t *= x; acc[3] += t; t *= x; acc[4] += t;
            }
        }
        // ---- image 1: diffs vs tvI/lpI + output moments ----
        {
            float A[10], B[10], C[10];
            load10(lds[1][rs - 1], x0, A);
            load10(lds[1][rs],     x0, B);
            load10(lds[1][rs + 1], x0, C);
            float c1[10], c2[10];
            #pragma unroll
            for (int j = 0; j < 10; j++) {
                c1[j] = A[j] + B[j] + C[j];
                c2[j] = fmaf(A[j], A[j], fmaf(B[j], B[j], C[j] * C[j]));
            }
            #pragma unroll
            for (int j = 0; j < 8; j++) {
                float s1 = c1[j] + c1[j+1] + c1[j+2];
                float s2 = c2[j] + c2[j+1] + c2[j+2];
                float mn = s1 * inv9;
                float tv = fmaf(-mn, mn, s2 * inv9);
                float lp = A[j+1] + C[j+1] + B[j] + B[j+2] - 4.0f * B[j+1];
                float m = mrow[j];
                acc[9]  += fabsf(tv * m - tvI[j] * m);
                acc[10] += fabsf(lp * m - lpI[j] * m);
                float x = B[j+1];
                float t = x * m; acc[5] += t; t *= x; acc[6] += t; t *= x; acc[7] += t; t *= x; acc[8] += t;
            }
        }
    }

    // ---- wave shuffle-reduce, then block reduce reusing the staging LDS ----
    #pragma unroll
    for (int q = 0; q < NQ; q++) {
        float v = acc[q];
        #pragma unroll
        for (int o = 32; o > 0; o >>= 1) v += __shfl_down(v, o);
        acc[q] = v;
    }
    __syncthreads();                  // all waves done reading staged data
    float* rf = (float*)lds;
    if (lane == 0) {
        #pragma unroll
        for (int q = 0; q < NQ; q++) rf[wib * NQ + q] = acc[q];
    }
    __syncthreads();

    // ---- tid0 publishes this block's 11 fp64 partials, then counts done ----
    if (tid == 0) {
        #pragma unroll
        for (int q = 0; q < NQ; q++) {
            double s = (double)rf[q] + (double)rf[NQ + q]
                     + (double)rf[2 * NQ + q] + (double)rf[3 * NQ + q];
            partials[(size_t)blk * NQ + q] = s;
        }
        __threadfence();                              // release partials device-wide
        unsigned old = atomicAdd(counter, 1u);        // device-scope by default
        amLast = (old == (unsigned)(nblk - 1));
    }
    __syncthreads();
    if (!amLast) return;

    // ---- last block: global reduce + loss math (fp64) ----
    __threadfence();                                  // acquire side
    double q[NQ];
    #pragma unroll
    for (int k = 0; k < NQ; k++) q[k] = 0.0;
    for (int i = tid; i < nblk; i += 256) {
        #pragma unroll
        for (int k = 0; k < NQ; k++)
            q[k] += __hip_atomic_load(&partials[(size_t)i * NQ + k],
                                      __ATOMIC_RELAXED, __HIP_MEMORY_SCOPE_AGENT);
    }
    #pragma unroll
    for (int k = 0; k < NQ; k++) {
        #pragma unroll
        for (int o = 32; o > 0; o >>= 1) q[k] += __shfl_down(q[k], o);
    }
    double* rd = (double*)lds;        // staging LDS free again; 4*11 doubles
    if (lane == 0) {
        #pragma unroll
        for (int k = 0; k < NQ; k++) rd[wib * NQ + k] = q[k];
    }
    __syncthreads();
    if (tid == 0) {
        double s[NQ];
        #pragma unroll
        for (int k = 0; k < NQ; k++)
            s[k] = rd[k] + rd[NQ + k] + rd[2 * NQ + k] + rd[3 * NQ + k];
        const double EPS = 1e-8;
        double S0 = s[0];
        double ms = S0 + EPS;
        double im = s[1] / ms, om = s[5] / ms;
        double im2 = im * im, im3 = im2 * im, im4 = im2 * im2;
        double om2 = om * om, om3 = om2 * om, om4 = om2 * om2;
        double di2 = s[2] - 2.0*im*s[1] + im2*S0;
        double do2 = s[6] - 2.0*om*s[5] + om2*S0;
        double iv = di2 / ms, ov = do2 / ms;
        double di3 = s[3] - 3.0*im*s[2] + 3.0*im2*s[1] - im3*S0;
        double do3 = s[7] - 3.0*om*s[6] + 3.0*om2*s[5] - om3*S0;
        double isk = di3 / (ms * (iv * sqrt(iv) + EPS));
        double osk = do3 / (ms * (ov * sqrt(ov) + EPS));
        double di4 = s[4] - 4.0*im*s[3] + 6.0*im2*s[2] - 4.0*im3*s[1] + im4*S0;
        double do4 = s[8] - 4.0*om*s[7] + 6.0*om2*s[6] - 4.0*om3*s[5] + om4*S0;
        double iku = di4 / (ms * (iv * iv + EPS));
        double oku = do4 / (ms * (ov * ov + EPS));
        double intensity = (im-om)*(im-om) + (iv-ov)*(iv-ov)
                         + (isk-osk)*(isk-osk) + (iku-oku)*(iku-oku);
        double texture = s[9]  * inv_n;
        double shape   = s[10] * inv_n;
        // TEXTURE_W=1.0, SHAPE_W=0.5, INTENSITY_W=1.0
        double total = intensity + texture + 0.5 * shape;
        out4[0] = (float)intensity;
        out4[1] = (float)texture;
        out4[2] = (float)shape;
        out4[3] = (float)total;
    }
}

extern "C" void kernel_launch(void* const* d_in, const int* in_sizes, int n_in,
                              void* d_out, int out_size, void* d_ws, size_t ws_size,
                              hipStream_t stream) {
    const float* inp  = (const float*)d_in[0];
    const float* outp = (const float*)d_in[1];
    const float* mask = (const float*)d_in[2];
    const int total = in_sizes[0];             // 32*1*512*512
    const int nimg  = total / (H * W);         // 32
    const int nblk  = nimg * (H / BAND);       // 2048 blocks of 256 threads

    unsigned int* counter = (unsigned int*)d_ws;              // first 1 KB: counter
    double* partials = (double*)((char*)d_ws + 1024);          // nblk*NQ doubles

    // zero the counter region (capturable async memset node; d_ws is poisoned 0xAA)
    hipMemsetAsync(d_ws, 0, 1024, stream);

    const double inv_n = 1.0 / (double)total;
    radiomics_fused<<<nblk, 256, 0, stream>>>(inp, outp, mask, partials,
                                              counter, nblk, inv_n, (float*)d_out);
}

// Round 8
// 133.229 us; speedup vs baseline: 1.5351x; 1.5351x over previous
//
#include <hip/hip_runtime.h>
#include <math.h>

#define H 512
#define W 512
#define BAND 4            // rows computed per band
#define STAGE 6           // rows staged per image (with halo)
#define NQ 11             // 0:s0 1-4:s1i..s4i 5-8:s1o..s4o 9:tex 10:shape
#define NBLK 1024         // persistent-ish grid; each block does 4 bands
#define ROUNDS 4          // 4096 bands / 1024 blocks

typedef __attribute__((address_space(3))) void       lds_void;
typedef const __attribute__((address_space(1))) void g_void;

// async global->LDS DMA, 16 B/lane: lane i's 16 B lands at l + i*16.
__device__ __forceinline__ void async_copy16(const float* g, float* l) {
    __builtin_amdgcn_global_load_lds((g_void*)g, (lds_void*)l, 16, 0, 0);
}

// read 8 px + 1-col halo each side from an LDS row; x0 is lane*8
__device__ __forceinline__ void load10(const float* row, int x0, float* a) {
    float4 u = *(const float4*)&row[x0];
    float4 v = *(const float4*)&row[x0 + 4];
    a[0] = (x0 == 0) ? 0.0f : row[x0 - 1];
    a[1] = u.x; a[2] = u.y; a[3] = u.z; a[4] = u.w;
    a[5] = v.x; a[6] = v.y; a[7] = v.z; a[8] = v.w;
    a[9] = (x0 + 8 == W) ? 0.0f : row[x0 + 8];
}

// Double-buffered LDS pipeline: DMA band k+1 (issued right after the barrier)
// overlaps compute of band k — ~2000 cyc load-to-use vs ~500 cyc L3 latency.
// 48 KB LDS -> 3 blocks/CU. No fences/atomics (r7 lesson). Two-kernel reduce.
__global__ __launch_bounds__(256) void radiomics_main(
    const float* __restrict__ inp, const float* __restrict__ outp,
    const float* __restrict__ mask, double* __restrict__ partials)
{
    __shared__ float lds[2][2][STAGE][W];   // [buf][img][row][col] = 49152 B

    const int tid  = threadIdx.x;
    const int lane = tid & 63;
    const int wib  = tid >> 6;              // wave in block; computes band row wib
    const int x0   = lane * 8;

    float acc[NQ];
    #pragma unroll
    for (int q = 0; q < NQ; q++) acc[q] = 0.0f;
    float Mk[8], Mn[8];
    const float inv9 = 1.0f / 9.0f;

    auto stage_band = [&](int band_id, int buf) {
        const int bimg = band_id >> 7;                    // image index
        const int y0   = (band_id & 127) * BAND;
        const size_t off = (size_t)bimg * H * W;
        #pragma unroll
        for (int s = wib; s < 2 * STAGE * 2; s += 4) {    // 24 segs of 1 KB, 6/wave
            const int img = (s >= 2 * STAGE);
            const int rem = s - img * 2 * STAGE;
            const int rs  = rem >> 1;
            const int g   = rem & 1;
            const int y   = y0 - 1 + rs;
            float* dst = &lds[buf][img][rs][g * 256];
            if (y < 0 || y >= H) {
                *(float4*)&dst[lane * 4] = make_float4(0.f, 0.f, 0.f, 0.f);
            } else {
                const float* src = (img ? outp : inp) + off + (size_t)y * W + g * 256 + lane * 4;
                async_copy16(src, dst);
            }
        }
    };
    auto load_mask8 = [&](int band_id, float* M) {
        const int bimg = band_id >> 7;
        const int y    = (band_id & 127) * BAND + wib;    // this wave's compute row
        const float4* p = (const float4*)(mask + (size_t)bimg * H * W + (size_t)y * W + x0);
        float4 a = p[0], c = p[1];
        M[0]=a.x; M[1]=a.y; M[2]=a.z; M[3]=a.w; M[4]=c.x; M[5]=c.y; M[6]=c.z; M[7]=c.w;
    };

    // ---- prologue: stage first band ----
    stage_band(blockIdx.x, 0);
    load_mask8(blockIdx.x, Mk);

    int cur = 0;
    #pragma unroll
    for (int k = 0; k < ROUNDS; k++) {
        __syncthreads();    // drains buf[cur] DMAs; all waves done reading buf[cur^1]

        if (k < ROUNDS - 1) {
            stage_band(blockIdx.x + (k + 1) * NBLK, cur ^ 1);   // overlaps compute below
            load_mask8(blockIdx.x + (k + 1) * NBLK, Mn);
        }

        // ---- compute this wave's row (stage row wib+1) from buf[cur] ----
        const int rs = wib + 1;
        float tvI[8], lpI[8];
        {   // image 0: texture/laplacian + input moments
            float A[10], B[10], C[10];
            load10(lds[cur][0][rs - 1], x0, A);
            load10(lds[cur][0][rs],     x0, B);
            load10(lds[cur][0][rs + 1], x0, C);
            float c1[10], c2[10];
            #pragma unroll
            for (int j = 0; j < 10; j++) {
                c1[j] = A[j] + B[j] + C[j];
                c2[j] = fmaf(A[j], A[j], fmaf(B[j], B[j], C[j] * C[j]));
            }
            #pragma unroll
            for (int j = 0; j < 8; j++) {
                float s1 = c1[j] + c1[j+1] + c1[j+2];
                float s2 = c2[j] + c2[j+1] + c2[j+2];
                float mn = s1 * inv9;
                tvI[j] = fmaf(-mn, mn, s2 * inv9);
                lpI[j] = A[j+1] + C[j+1] + B[j] + B[j+2] - 4.0f * B[j+1];
                float m = Mk[j];
                acc[0] += m;
                float x = B[j+1];
                float t = x * m; acc[1] += t; t *= x; acc[2] += t; t *= x; acc[3] += t; t *= x; acc[4] += t;
            }
        }
        {   // image 1: diffs vs tvI/lpI + output moments
            float A[10], B[10], C[10];
            load10(lds[cur][1][rs - 1], x0, A);
            load10(lds[cur][1][rs],     x0, B);
            load10(lds[cur][1][rs + 1], x0, C);
            float c1[10], c2[10];
            #pragma unroll
            for (int j = 0; j < 10; j++) {
                c1[j] = A[j] + B[j] + C[j];
                c2[j] = fmaf(A[j], A[j], fmaf(B[j], B[j], C[j] * C[j]));
            }
            #pragma unroll
            for (int j = 0; j < 8; j++) {
                float s1 = c1[j] + c1[j+1] + c1[j+2];
                float s2 = c2[j] + c2[j+1] + c2[j+2];
                float mn = s1 * inv9;
                float tv = fmaf(-mn, mn, s2 * inv9);
                float lp = A[j+1] + C[j+1] + B[j] + B[j+2] - 4.0f * B[j+1];
                float m = Mk[j];
                acc[9]  += fabsf(tv * m - tvI[j] * m);
                acc[10] += fabsf(lp * m - lpI[j] * m);
                float x = B[j+1];
                float t = x * m; acc[5] += t; t *= x; acc[6] += t; t *= x; acc[7] += t; t *= x; acc[8] += t;
            }
        }

        if (k < ROUNDS - 1) {
            #pragma unroll
            for (int j = 0; j < 8; j++) Mk[j] = Mn[j];
        }
        cur ^= 1;
    }

    // ---- wave shuffle-reduce, then block reduce via LDS scratch ----
    #pragma unroll
    for (int q = 0; q < NQ; q++) {
        float v = acc[q];
        #pragma unroll
        for (int o = 32; o > 0; o >>= 1) v += __shfl_down(v, o);
        acc[q] = v;
    }
    __syncthreads();                  // all waves done with staged data
    float* rf = (float*)lds;
    if (lane == 0) {
        #pragma unroll
        for (int q = 0; q < NQ; q++) rf[wib * NQ + q] = acc[q];
    }
    __syncthreads();
    if (tid < NQ) {
        double s = (double)rf[tid] + (double)rf[NQ + tid]
                 + (double)rf[2 * NQ + tid] + (double)rf[3 * NQ + tid];
        partials[(size_t)blockIdx.x * NQ + tid] = s;
    }
}

__global__ __launch_bounds__(256) void radiomics_final(
    const double* __restrict__ partials, int nblk, float* __restrict__ out4, double inv_n)
{
    const int tid = threadIdx.x;
    const int lane = tid & 63;
    const int w = tid >> 6;
    double q[NQ];
    #pragma unroll
    for (int k = 0; k < NQ; k++) q[k] = 0.0;
    for (int i = tid; i < nblk; i += 256) {
        #pragma unroll
        for (int k = 0; k < NQ; k++) q[k] += partials[(size_t)i * NQ + k];
    }
    #pragma unroll
    for (int k = 0; k < NQ; k++) {
        #pragma unroll
        for (int o = 32; o > 0; o >>= 1) q[k] += __shfl_down(q[k], o);
    }
    __shared__ double red[4][NQ];
    if (lane == 0) {
        #pragma unroll
        for (int k = 0; k < NQ; k++) red[w][k] = q[k];
    }
    __syncthreads();
    if (tid == 0) {
        double s[NQ];
        #pragma unroll
        for (int k = 0; k < NQ; k++) s[k] = red[0][k] + red[1][k] + red[2][k] + red[3][k];
        const double EPS = 1e-8;
        double S0 = s[0];
        double ms = S0 + EPS;
        double im = s[1] / ms, om = s[5] / ms;
        double im2 = im * im, im3 = im2 * im, im4 = im2 * im2;
        double om2 = om * om, om3 = om2 * om, om4 = om2 * om2;
        double di2 = s[2] - 2.0*im*s[1] + im2*S0;
        double do2 = s[6] - 2.0*om*s[5] + om2*S0;
        double iv = di2 / ms, ov = do2 / ms;
        double di3 = s[3] - 3.0*im*s[2] + 3.0*im2*s[1] - im3*S0;
        double do3 = s[7] - 3.0*om*s[6] + 3.0*om2*s[5] - om3*S0;
        double isk = di3 / (ms * (iv * sqrt(iv) + EPS));
        double osk = do3 / (ms * (ov * sqrt(ov) + EPS));
        double di4 = s[4] - 4.0*im*s[3] + 6.0*im2*s[2] - 4.0*im3*s[1] + im4*S0;
        double do4 = s[8] - 4.0*om*s[7] + 6.0*om2*s[6] - 4.0*om3*s[5] + om4*S0;
        double iku = di4 / (ms * (iv * iv + EPS));
        double oku = do4 / (ms * (ov * ov + EPS));
        double intensity = (im-om)*(im-om) + (iv-ov)*(iv-ov)
                         + (isk-osk)*(isk-osk) + (iku-oku)*(iku-oku);
        double texture = s[9]  * inv_n;
        double shape   = s[10] * inv_n;
        // TEXTURE_W=1.0, SHAPE_W=0.5, INTENSITY_W=1.0
        double total = intensity + texture + 0.5 * shape;
        out4[0] = (float)intensity;
        out4[1] = (float)texture;
        out4[2] = (float)shape;
        out4[3] = (float)total;
    }
}

extern "C" void kernel_launch(void* const* d_in, const int* in_sizes, int n_in,
                              void* d_out, int out_size, void* d_ws, size_t ws_size,
                              hipStream_t stream) {
    const float* inp  = (const float*)d_in[0];
    const float* outp = (const float*)d_in[1];
    const float* mask = (const float*)d_in[2];
    const int total = in_sizes[0];             // 32*1*512*512
    double* partials = (double*)d_ws;          // NBLK*NQ doubles, fully overwritten

    radiomics_main<<<NBLK, 256, 0, stream>>>(inp, outp, mask, partials);
    const double inv_n = 1.0 / (double)total;
    radiomics_final<<<1, 256, 0, stream>>>(partials, NBLK, (float*)d_out, inv_n);
}